// Round 7
// baseline (177.231 us; speedup 1.0000x reference)
//
#include <hip/hip_runtime.h>

#define GRID_RES 128
#define N_RAYS 65536
#define N_STEPS 128
#define STEP_SIZE 0.001f

__device__ __forceinline__ float sigmoidf_fast(float x) {
    return 1.0f / (1.0f + __expf(-x));
}

// cross-lane sum over aligned groups of 8 lanes
__device__ __forceinline__ float oct_dpp_xor1(float x) {
    return __int_as_float(__builtin_amdgcn_update_dpp(0, __float_as_int(x), 0xB1, 0xF, 0xF, true)); // quad_perm [1,0,3,2]
}
__device__ __forceinline__ float oct_dpp_xor2(float x) {
    return __int_as_float(__builtin_amdgcn_update_dpp(0, __float_as_int(x), 0x4E, 0xF, 0xF, true)); // quad_perm [2,3,0,1]
}
__device__ __forceinline__ float oct_swz_xor4(float x) {
    // ds_swizzle BitMode: offset = (xor_mask<<10) | (0<<5) | and_mask(0x1F) -> lane ^= 4
    return __int_as_float(__builtin_amdgcn_ds_swizzle(__float_as_int(x), 0x101F));
}
__device__ __forceinline__ float oct_sum(float x) {
    x += oct_dpp_xor1(x);
    x += oct_dpp_xor2(x);
    x += oct_swz_xor4(x);
    return x;
}

__global__ __launch_bounds__(256, 8) void vr_kernel(
    const float* __restrict__ data,
    const float* __restrict__ origins,
    const float* __restrict__ dirs,
    const float* __restrict__ viewdirs,
    float* __restrict__ out)
{
    int gid = blockIdx.x * blockDim.x + threadIdx.x;
    int ray = gid >> 3;        // 8 cooperative lanes per ray
    int l   = gid & 7;

    float ox = origins[3*ray+0], oy = origins[3*ray+1], oz = origins[3*ray+2];
    float dx = dirs[3*ray+0],    dy = dirs[3*ray+1],    dz = dirs[3*ray+2];
    float vx = viewdirs[3*ray+0], vy = viewdirs[3*ray+1], vz = viewdirs[3*ray+2];

    // normalize (numpy rounding: no fma contraction, sqrt+divide)
    {
        float s = __fadd_rn(__fadd_rn(__fmul_rn(dx,dx), __fmul_rn(dy,dy)), __fmul_rn(dz,dz));
        float n = sqrtf(s);
        dx = __fdiv_rn(dx, n); dy = __fdiv_rn(dy, n); dz = __fdiv_rn(dz, n);
    }
    {
        float s = __fadd_rn(__fadd_rn(__fmul_rn(vx,vx), __fmul_rn(vy,vy)), __fmul_rn(vz,vz));
        float n = sqrtf(s);
        vx = __fdiv_rn(vx, n); vy = __fdiv_rn(vy, n); vz = __fdiv_rn(vz, n);
    }

    float invx = __fdiv_rn(1.0f, __fadd_rn(dx, 1e-9f));
    float invy = __fdiv_rn(1.0f, __fadd_rn(dy, 1e-9f));
    float invz = __fdiv_rn(1.0f, __fadd_rn(dz, 1e-9f));

    float t1x = __fmul_rn(-ox, invx), t1y = __fmul_rn(-oy, invy), t1z = __fmul_rn(-oz, invz);
    float t2x = __fadd_rn(t1x, invx), t2y = __fadd_rn(t1y, invy), t2z = __fadd_rn(t1z, invz);
    float tmin = fmaxf(fmaxf(fminf(t1x,t2x), fminf(t1y,t2y)), fminf(t1z,t2z));
    tmin = fmaxf(tmin, 0.0f);
    float tmax = fminf(fminf(fmaxf(t1x,t2x), fmaxf(t1y,t2y)), fmaxf(t1z,t2z));
    tmax = fminf(tmax, 1e9f);
    float dt = __fmul_rn(fmaxf(__fsub_rn(tmax, tmin), 0.0f), (1.0f/(float)N_STEPS));
    float delta_t = __fadd_rn(dt, STEP_SIZE);

    // SH basis
    const float sh0 = 0.28209479177387814f;
    float sh1 = -0.4886025119029199f * vy;
    float sh2 =  0.4886025119029199f * vz;
    float sh3 = -0.4886025119029199f * vx;
    float sh4 =  1.0925484305920792f * vx * vy;
    float sh5 = -1.0925484305920792f * vy * vz;
    float sh6 =  0.31539156525252005f * (2.0f*vz*vz - vx*vx - vy*vy);
    float sh7 = -1.0925484305920792f * vx * vz;
    float sh8 =  0.5462742152960396f * (vx*vx - vy*vy);

    // Per-lane channel-routed weights for comps c = 4l..4l+3 (lane 7: zeros).
    float wr[4], wg[4], wb[4];
    #pragma unroll
    for (int m = 0; m < 4; ++m) {
        int c  = (l < 7) ? (4*l + m) : 27;   // 27 -> all three masks false
        int cb = c % 9;
        float s = sh0;
        s = (cb==1) ? sh1 : s;
        s = (cb==2) ? sh2 : s;
        s = (cb==3) ? sh3 : s;
        s = (cb==4) ? sh4 : s;
        s = (cb==5) ? sh5 : s;
        s = (cb==6) ? sh6 : s;
        s = (cb==7) ? sh7 : s;
        s = (cb==8) ? sh8 : s;
        wr[m] = (c < 9)            ? s : 0.0f;
        wg[m] = (c >= 9 && c < 18) ? s : 0.0f;
        wb[m] = (c >= 18 && c < 27)? s : 0.0f;
    }

    // one float4 per lane: comps 4l..4l+3 (lane 7 dups comps 24..27, zero-weighted)
    unsigned offC = (l < 7) ? (4u * (unsigned)l) : 24u;

    // voxel linear index for step i — bit-identical to the validated chain
    auto linidx = [&](int i) -> unsigned {
        float t = __fadd_rn(tmin, __fmul_rn((float)i + 0.5f, dt));
        float px = __fadd_rn(ox, __fmul_rn(t, dx));
        float py = __fadd_rn(oy, __fmul_rn(t, dy));
        float pz = __fadd_rn(oz, __fmul_rn(t, dz));
        int ix = (int)(px * (float)GRID_RES);
        int iy = (int)(py * (float)GRID_RES);
        int iz = (int)(pz * (float)GRID_RES);
        ix = min(max(ix, 0), GRID_RES-1);
        iy = min(max(iy, 0), GRID_RES-1);
        iz = min(max(iz, 0), GRID_RES-1);
        return (unsigned)(((ix << 7) | iy) << 7 | iz);
    };

    float light = 1.0f;
    float o_r = 0.0f, o_g = 0.0f, o_b = 0.0f;

    // ---- 3-stage pipeline: sigma(i+2) || coeffs(i+1) || shade(i) ----
    // sigma: 4B load, same address across the 8 lanes (one sector).
    // coeffs: address redirected to hot array base when sigma<=0.
    unsigned lin1;
    float s0, s1;
    float4 C0;
    {
        unsigned lin0 = linidx(0);
        lin1 = linidx(1);
        s0 = data[28u * lin0 + 27u];
        s1 = data[28u * lin1 + 27u];
        const float* rec0 = (s0 > 0.0f) ? (data + 28u * lin0) : data;
        C0 = *(const float4*)(rec0 + offC);
    }

    for (int i = 0; i < N_STEPS; ++i) {
        unsigned lin2 = linidx(i + 2);
        float s2 = data[28u * lin2 + 27u];

        const float* rec1 = (s1 > 0.0f) ? (data + 28u * lin1) : data;
        float4 C1 = *(const float4*)(rec1 + offC);

        float sigma = fmaxf(s0, 0.0f);
        float att = __expf(-delta_t * sigma);
        float w = light * (1.0f - att);

        float pr = wr[0]*C0.x + wr[1]*C0.y + wr[2]*C0.z + wr[3]*C0.w;
        float pg = wg[0]*C0.x + wg[1]*C0.y + wg[2]*C0.z + wg[3]*C0.w;
        float pb = wb[0]*C0.x + wb[1]*C0.y + wb[2]*C0.z + wb[3]*C0.w;

        float r = oct_sum(pr);
        float g = oct_sum(pg);
        float b = oct_sum(pb);

        o_r = fmaf(w, sigmoidf_fast(r), o_r);
        o_g = fmaf(w, sigmoidf_fast(g), o_g);
        o_b = fmaf(w, sigmoidf_fast(b), o_b);
        light *= att;

        s0 = s1; s1 = s2;
        lin1 = lin2;
        C0 = C1;
    }

    if (l == 0) {
        out[3*ray+0] = o_r + light;   // BG = 1.0
        out[3*ray+1] = o_g + light;
        out[3*ray+2] = o_b + light;
    }
}

extern "C" void kernel_launch(void* const* d_in, const int* in_sizes, int n_in,
                              void* d_out, int out_size, void* d_ws, size_t ws_size,
                              hipStream_t stream) {
    const float* data     = (const float*)d_in[0];
    const float* origins  = (const float*)d_in[1];
    const float* dirs     = (const float*)d_in[2];
    const float* viewdirs = (const float*)d_in[3];
    float* out = (float*)d_out;

    dim3 block(256);
    dim3 grid((N_RAYS * 8) / 256);
    vr_kernel<<<grid, block, 0, stream>>>(data, origins, dirs, viewdirs, out);
}

// Round 8
// 129.443 us; speedup vs baseline: 1.3692x; 1.3692x over previous
//
#include <hip/hip_runtime.h>

#define GRID_RES 128
#define N_RAYS 65536
#define N_STEPS 128
#define STEP_SIZE 0.001f

__device__ __forceinline__ float rcp_fast(float x) {
    return __builtin_amdgcn_rcpf(x);   // v_rcp_f32, ~1 ulp
}
__device__ __forceinline__ float sigmoidf_fast(float x) {
    return rcp_fast(1.0f + __expf(-x));
}

// DPP quad_perm helpers (cross-lane within aligned groups of 4 lanes)
__device__ __forceinline__ float quad_dpp_xor1(float x) {
    return __int_as_float(__builtin_amdgcn_update_dpp(0, __float_as_int(x), 0xB1, 0xF, 0xF, true)); // [1,0,3,2]
}
__device__ __forceinline__ float quad_dpp_xor2(float x) {
    return __int_as_float(__builtin_amdgcn_update_dpp(0, __float_as_int(x), 0x4E, 0xF, 0xF, true)); // [2,3,0,1]
}
__device__ __forceinline__ float quad_sum(float x) {
    x += quad_dpp_xor1(x);
    x += quad_dpp_xor2(x);
    return x;
}

__global__ __launch_bounds__(256, 4) void vr_kernel(
    const float* __restrict__ data,
    const float* __restrict__ origins,
    const float* __restrict__ dirs,
    const float* __restrict__ viewdirs,
    float* __restrict__ out)
{
    int gid = blockIdx.x * blockDim.x + threadIdx.x;
    int ray = gid >> 2;        // 4 cooperative lanes per ray
    int l   = gid & 3;

    float ox = origins[3*ray+0], oy = origins[3*ray+1], oz = origins[3*ray+2];
    float dx = dirs[3*ray+0],    dy = dirs[3*ray+1],    dz = dirs[3*ray+2];
    float vx = viewdirs[3*ray+0], vy = viewdirs[3*ray+1], vz = viewdirs[3*ray+2];

    // normalize (numpy rounding: no fma contraction, sqrt+divide)
    {
        float s = __fadd_rn(__fadd_rn(__fmul_rn(dx,dx), __fmul_rn(dy,dy)), __fmul_rn(dz,dz));
        float n = sqrtf(s);
        dx = __fdiv_rn(dx, n); dy = __fdiv_rn(dy, n); dz = __fdiv_rn(dz, n);
    }
    {
        float s = __fadd_rn(__fadd_rn(__fmul_rn(vx,vx), __fmul_rn(vy,vy)), __fmul_rn(vz,vz));
        float n = sqrtf(s);
        vx = __fdiv_rn(vx, n); vy = __fdiv_rn(vy, n); vz = __fdiv_rn(vz, n);
    }

    float invx = __fdiv_rn(1.0f, __fadd_rn(dx, 1e-9f));
    float invy = __fdiv_rn(1.0f, __fadd_rn(dy, 1e-9f));
    float invz = __fdiv_rn(1.0f, __fadd_rn(dz, 1e-9f));

    float t1x = __fmul_rn(-ox, invx), t1y = __fmul_rn(-oy, invy), t1z = __fmul_rn(-oz, invz);
    float t2x = __fadd_rn(t1x, invx), t2y = __fadd_rn(t1y, invy), t2z = __fadd_rn(t1z, invz);
    float tmin = fmaxf(fmaxf(fminf(t1x,t2x), fminf(t1y,t2y)), fminf(t1z,t2z));
    tmin = fmaxf(tmin, 0.0f);
    float tmax = fminf(fminf(fmaxf(t1x,t2x), fmaxf(t1y,t2y)), fmaxf(t1z,t2z));
    tmax = fminf(tmax, 1e9f);
    float dt = __fmul_rn(fmaxf(__fsub_rn(tmax, tmin), 0.0f), (1.0f/(float)N_STEPS));
    float delta_t = __fadd_rn(dt, STEP_SIZE);

    // SH basis
    const float sh0 = 0.28209479177387814f;
    float sh1 = -0.4886025119029199f * vy;
    float sh2 =  0.4886025119029199f * vz;
    float sh3 = -0.4886025119029199f * vx;
    float sh4 =  1.0925484305920792f * vx * vy;
    float sh5 = -1.0925484305920792f * vy * vz;
    float sh6 =  0.31539156525252005f * (2.0f*vz*vz - vx*vx - vy*vy);
    float sh7 = -1.0925484305920792f * vx * vz;
    float sh8 =  0.5462742152960396f * (vx*vx - vy*vy);

    // Per-lane channel-routed weights for components c = 8l..8l+7 (zeros off-channel).
    float wr[8], wg_[8], wb[8];
    #pragma unroll
    for (int m = 0; m < 8; ++m) {
        int c  = 8*l + m;
        int cb = c % 9;
        float s = sh0;
        s = (cb==1) ? sh1 : s;
        s = (cb==2) ? sh2 : s;
        s = (cb==3) ? sh3 : s;
        s = (cb==4) ? sh4 : s;
        s = (cb==5) ? sh5 : s;
        s = (cb==6) ? sh6 : s;
        s = (cb==7) ? sh7 : s;
        s = (cb==8) ? sh8 : s;
        wr[m]  = (c < 9)            ? s : 0.0f;
        wg_[m] = (c >= 9 && c < 18) ? s : 0.0f;
        wb[m]  = (c >= 18 && c < 27)? s : 0.0f;
    }

    unsigned offA = 8u * (unsigned)l;
    unsigned offB = (l < 3) ? (8u * (unsigned)l + 4u) : 24u;

    // voxel linear index for step i — bit-identical to the validated chain
    auto linidx = [&](int i) -> unsigned {
        float t = __fadd_rn(tmin, __fmul_rn((float)i + 0.5f, dt));
        float px = __fadd_rn(ox, __fmul_rn(t, dx));
        float py = __fadd_rn(oy, __fmul_rn(t, dy));
        float pz = __fadd_rn(oz, __fmul_rn(t, dz));
        int ix = (int)(px * (float)GRID_RES);
        int iy = (int)(py * (float)GRID_RES);
        int iz = (int)(pz * (float)GRID_RES);
        ix = min(max(ix, 0), GRID_RES-1);
        iy = min(max(iy, 0), GRID_RES-1);
        iz = min(max(iz, 0), GRID_RES-1);
        return (unsigned)(((ix << 7) | iy) << 7 | iz);
    };

    float light = 1.0f;
    float o_r = 0.0f, o_g = 0.0f, o_b = 0.0f;

    auto shade = [&](float s, const float4& A, const float4& B) {
        float sigma = fmaxf(s, 0.0f);
        float att = __expf(-delta_t * sigma);
        float w = light * (1.0f - att);

        float pr = wr[0]*A.x + wr[1]*A.y + wr[2]*A.z + wr[3]*A.w
                 + wr[4]*B.x + wr[5]*B.y + wr[6]*B.z + wr[7]*B.w;
        float pg = wg_[0]*A.x + wg_[1]*A.y + wg_[2]*A.z + wg_[3]*A.w
                 + wg_[4]*B.x + wg_[5]*B.y + wg_[6]*B.z + wg_[7]*B.w;
        float pb = wb[0]*A.x + wb[1]*A.y + wb[2]*A.z + wb[3]*A.w
                 + wb[4]*B.x + wb[5]*B.y + wb[6]*B.z + wb[7]*B.w;

        float r = quad_sum(pr);
        float g = quad_sum(pg);
        float b = quad_sum(pb);

        o_r = fmaf(w, sigmoidf_fast(r), o_r);
        o_g = fmaf(w, sigmoidf_fast(g), o_g);
        o_b = fmaf(w, sigmoidf_fast(b), o_b);
        light *= att;
    };

    // ---- unroll-2 deep pipeline ----
    // per body (pair i,i+1): issue sigma(i+4),sigma(i+5); issue gated coeffs(i+2),(i+3);
    // shade(i),(i+1). Every load has >=2 bodies of slack.
    float sA, sB, sC, sD;            // sigma for i, i+1, i+2, i+3
    float4 CAa, CAb, CBa, CBb;       // coeffs for i, i+1
    unsigned linP, linQ;             // voxel index for i+2, i+3
    {
        unsigned lin0 = linidx(0), lin1 = linidx(1);
        linP = linidx(2); linQ = linidx(3);
        sA = data[28u*lin0 + 27u];
        sB = data[28u*lin1 + 27u];
        sC = data[28u*linP + 27u];
        sD = data[28u*linQ + 27u];
        const float* r0 = (sA > 0.0f) ? (data + 28u*lin0) : data;
        CAa = *(const float4*)(r0 + offA);
        CAb = *(const float4*)(r0 + offB);
        const float* r1 = (sB > 0.0f) ? (data + 28u*lin1) : data;
        CBa = *(const float4*)(r1 + offA);
        CBb = *(const float4*)(r1 + offB);
    }

    #pragma unroll 1
    for (int i = 0; i < N_STEPS; i += 2) {
        // stage 1: sigma 4-5 steps ahead (clamped index math is safe past 127)
        unsigned lin4 = linidx(i + 4);
        unsigned lin5 = linidx(i + 5);
        float sE = data[28u*lin4 + 27u];
        float sF = data[28u*lin5 + 27u];

        // stage 2: gated coefficients 2-3 steps ahead
        const float* rp = (sC > 0.0f) ? (data + 28u*linP) : data;
        float4 CCa = *(const float4*)(rp + offA);
        float4 CCb = *(const float4*)(rp + offB);
        const float* rq = (sD > 0.0f) ? (data + 28u*linQ) : data;
        float4 CDa = *(const float4*)(rq + offA);
        float4 CDb = *(const float4*)(rq + offB);

        // stage 3: shade steps i and i+1
        shade(sA, CAa, CAb);
        shade(sB, CBa, CBb);

        // shift (all static names — no dynamic register indexing)
        sA = sC; sB = sD; sC = sE; sD = sF;
        CAa = CCa; CAb = CCb; CBa = CDa; CBb = CDb;
        linP = lin4; linQ = lin5;
    }

    if (l == 0) {
        out[3*ray+0] = o_r + light;   // BG = 1.0
        out[3*ray+1] = o_g + light;
        out[3*ray+2] = o_b + light;
    }
}

extern "C" void kernel_launch(void* const* d_in, const int* in_sizes, int n_in,
                              void* d_out, int out_size, void* d_ws, size_t ws_size,
                              hipStream_t stream) {
    const float* data     = (const float*)d_in[0];
    const float* origins  = (const float*)d_in[1];
    const float* dirs     = (const float*)d_in[2];
    const float* viewdirs = (const float*)d_in[3];
    float* out = (float*)d_out;

    dim3 block(256);
    dim3 grid((N_RAYS * 4) / 256);
    vr_kernel<<<grid, block, 0, stream>>>(data, origins, dirs, viewdirs, out);
}